// Round 25
// baseline (157.435 us; speedup 1.0000x reference)
//
#include <hip/hip_runtime.h>
#include <hip/hip_bf16.h>

typedef __bf16 bf16;
typedef __bf16 bf16x4 __attribute__((ext_vector_type(4)));
typedef __bf16 bf16x8 __attribute__((ext_vector_type(8)));
typedef float f32x4 __attribute__((ext_vector_type(4)));
typedef unsigned int u32x4 __attribute__((ext_vector_type(4)));

#define SEQ   2048
#define NBAT  4
#define DM    1024
#define NH    16
#define HD    64
#define E3    3072
#define E2    2048   // Z2 row stride: [K(0:1024) | Q_scaled(1024:2048)]

#define SL2E_C 0.04508422f   // (1/32) * log2(e)

// ---------------- fp32 -> bf16 convert (x and W fused in one launch) ----------------
__global__ void cvt2_bf16_kernel(const float* __restrict__ a, bf16* __restrict__ oa, int na8,
                                 const float* __restrict__ b, bf16* __restrict__ ob, int nb8) {
  const int stride = gridDim.x * blockDim.x;
  const int ntot = na8 + nb8;
  for (int i = blockIdx.x * blockDim.x + threadIdx.x; i < ntot; i += stride) {
    const float* src;
    bf16* dst;
    int j;
    if (i < na8) { src = a; dst = oa; j = i; }
    else         { src = b; dst = ob; j = i - na8; }
    const float4* p = (const float4*)(src + (size_t)j * 8);
    float4 x = p[0];
    float4 y = p[1];
    bf16x8 o;
    o[0] = (bf16)x.x; o[1] = (bf16)x.y; o[2] = (bf16)x.z; o[3] = (bf16)x.w;
    o[4] = (bf16)y.x; o[5] = (bf16)y.y; o[6] = (bf16)y.z; o[7] = (bf16)y.w;
    *(bf16x8*)(dst + (size_t)j * 8) = o;
  }
}

// ---------------- QKV projection GEMM ----------------
// Grid is 1D (1536 blocks) with an XCD-chunked decode: XCD x = flat&7 owns
// by in {3x..3x+2} (B working set 2.25MB -> L2-resident per XCD for the
// whole kernel; A streamed once per XCD from L3). bx iterates fastest
// within a by so consecutive co-resident blocks share the B-panel.
// K cols (col<1024)        -> Z2[row][col] row-major.
// Q cols (1024<=col<2048)  -> Z2[row][col] PRE-SCALED by scale*log2e.
// V cols (col>=2048)       -> VT[n][h][d][k'] with sigma pre-applied.
#define BM 128
#define BN 128
#define BK 32
#define KSTEPS (DM / BK)

__global__ __launch_bounds__(256, 2) void qkv_gemm_kernel(
    const bf16* __restrict__ A, const bf16* __restrict__ B,
    const float* __restrict__ bias, bf16* __restrict__ Z2, bf16* __restrict__ VT)
{
  __shared__ bf16 sA[2][BM * BK];
  __shared__ bf16 sB[2][BN * BK];

  const int tid  = threadIdx.x;
  const int lane = tid & 63;
  const int w    = tid >> 6;
  const int wr   = w >> 1;
  const int wc   = w & 1;

  // XCD-chunked decode (1536 = 8 XCDs x 3 by-panels x 64 bx)
  const int flat = blockIdx.x;
  const int xcd  = flat & 7;
  const int i2   = flat >> 3;            // 0..191
  const int by   = 3 * xcd + (i2 >> 6);  // 0..23
  const int bx   = i2 & 63;              // 0..63
  const int m0   = bx * BM;
  const int n0   = by * BN;

  const f32x4 z4 = {0.f, 0.f, 0.f, 0.f};
  f32x4 acc[4][4];
#pragma unroll
  for (int i = 0; i < 4; ++i)
#pragma unroll
    for (int j = 0; j < 4; ++j)
      acc[i][j] = z4;

  const int srow = w * 32 + (lane >> 2);
  const int skk  = (lane & 3) * 8;
  const bf16* gA = A + (size_t)m0 * DM;
  const bf16* gB = B + (size_t)n0 * DM;

  auto stage = [&](int buf, int t) {
    const int k0 = t * BK;
#pragma unroll
    for (int c = 0; c < 2; ++c)
      __builtin_amdgcn_global_load_lds(
          (const __attribute__((address_space(1))) unsigned int*)(gA + (size_t)(srow + c * 16) * DM + k0 + skk),
          (__attribute__((address_space(3))) unsigned int*)(&sA[buf][w * 1024 + c * 512]),
          16, 0, 0);
#pragma unroll
    for (int c = 0; c < 2; ++c)
      __builtin_amdgcn_global_load_lds(
          (const __attribute__((address_space(1))) unsigned int*)(gB + (size_t)(srow + c * 16) * DM + k0 + skk),
          (__attribute__((address_space(3))) unsigned int*)(&sB[buf][w * 1024 + c * 512]),
          16, 0, 0);
  };

  stage(0, 0);
  int cur = 0;
  const int arow = wr * 64 + (lane & 15);
  const int brow = wc * 64 + (lane & 15);
  const int kf   = (lane >> 4) * 8;

  for (int t = 0; t < KSTEPS; ++t) {
    __syncthreads();
    if (t + 1 < KSTEPS) stage(cur ^ 1, t + 1);
    bf16x8 af[4], bfr[4];
#pragma unroll
    for (int i = 0; i < 4; ++i)
      af[i] = *(const bf16x8*)&sA[cur][(arow + i * 16) * BK + kf];
#pragma unroll
    for (int j = 0; j < 4; ++j)
      bfr[j] = *(const bf16x8*)&sB[cur][(brow + j * 16) * BK + kf];
#pragma unroll
    for (int i = 0; i < 4; ++i)
#pragma unroll
      for (int j = 0; j < 4; ++j)
        acc[i][j] = __builtin_amdgcn_mfma_f32_16x16x32_bf16(af[i], bfr[j], acc[i][j], 0, 0, 0);
    cur ^= 1;
  }

  if (n0 < 2048) {
    // K/Q block: row-major Z2; Q columns pre-scaled by scale*log2e (fp32)
    const float sc = (n0 >= 1024) ? SL2E_C : 1.0f;
#pragma unroll
    for (int i = 0; i < 4; ++i) {
#pragma unroll
      for (int j = 0; j < 4; ++j) {
        const int col = n0 + wc * 64 + j * 16 + (lane & 15);
        const float bb = bias[col];
#pragma unroll
        for (int r = 0; r < 4; ++r) {
          const int row = m0 + wr * 64 + i * 16 + (lane >> 4) * 4 + r;
          Z2[(size_t)row * E2 + col] = (bf16)((acc[i][j][r] + bb) * sc);
        }
      }
    }
  } else {
    // V block: transposed, sigma-permuted VT[n][h][d][k'] (b64 stores)
#pragma unroll
    for (int i = 0; i < 4; ++i) {
      const int rowb = m0 + wr * 64 + i * 16 + (lane >> 4) * 4;
      const int nb   = rowb >> 11;
      const int k    = rowb & 2047;
      const int ksig = (k & ~63) | (k & 32) | (((k >> 2) & 3) << 3) | (((k >> 4) & 1) << 2);
#pragma unroll
      for (int j = 0; j < 4; ++j) {
        const int col  = n0 + wc * 64 + j * 16 + (lane & 15);
        const float bb = bias[col];
        const int colv = col - 2048;
        const int h    = colv >> 6;
        const int d    = colv & 63;
        bf16x4 v4;
#pragma unroll
        for (int r = 0; r < 4; ++r) v4[r] = (bf16)(acc[i][j][r] + bb);
        *(bf16x4*)&VT[(((size_t)nb * NH + h) * HD + d) * SEQ + ksig] = v4;
      }
    }
  }
}

// ---------------- causal flash attention ----------------
// r24 champion body, unchanged: QB = KB = 64, 4 waves x 16 q-rows, 32 qtiles
// pair-scheduled (b, 31-b) -> 1024 UNIFORM blocks, 4/CU. XCD-local remap.
// Swapped QK^T, NO-MAX softmax (scale folded into Q by the GEMM), ones-MFMA
// denominator, all-DMA K/V staging, sigma-contiguous b128 sVT reads.
#define QB 64
#define KB 64
#define NQT (SEQ / QB)   // 32

__global__ __launch_bounds__(256, 4) void attn_kernel(
    const bf16* __restrict__ Z2, const bf16* __restrict__ VT, float* __restrict__ out)
{
  __shared__ bf16 sK[2][KB][64];    // [buf][k][swizzled d]    16 KB
  __shared__ bf16 sVT[2][HD][64];   // [buf][d][sigma(k)^X(d)] 16 KB

  const int tid   = threadIdx.x;
  const int lane  = tid & 63;
  const int w     = tid >> 6;        // 0..3
  const int l15   = lane & 15;
  const int lhi   = lane >> 4;
  const int l7    = l15 & 7;
  const int e2    = l15 >> 3;        // 0/1

  const int flat  = blockIdx.x;
  const int xcd   = flat & 7;
  const int u     = flat >> 3;          // 0..127
  const int ctx   = xcd * 8 + (u & 7);
  const int pairb = u >> 3;             // 0..15
  const int h     = ctx & 15;
  const int n     = ctx >> 4;

  const size_t zb2 = (size_t)n * SEQ * E2;
  const size_t vtb = ((size_t)n * NH + h) * HD * SEQ;
  const int kcol0 = h * HD;
  const int qcol0 = DM + h * HD;

  const f32x4 z4 = {0.f, 0.f, 0.f, 0.f};
  const f32x4 neg4 = {-1e32f, -1e32f, -1e32f, -1e32f};

  const u32x4 onesu = {0x3F803F80u, 0x3F803F80u, 0x3F803F80u, 0x3F803F80u};
  const bf16x8 onesf = __builtin_bit_cast(bf16x8, onesu);

  const int krow_in = lane >> 3;                        // 0..7 within chunk
  const int kdblk   = ((lane & 7) ^ (lane >> 3)) * 8;   // swizzled d offset

  const size_t ob = (size_t)n * SEQ * DM;

  auto stageK = [&](int t, int buf) {
#pragma unroll
    for (int c = 0; c < 2; ++c) {
      const int cc = 2 * w + c;
      __builtin_amdgcn_global_load_lds(
          (const __attribute__((address_space(1))) unsigned int*)(
              Z2 + zb2 + (size_t)(t * KB + 8 * cc + krow_in) * E2 + kcol0 + kdblk),
          (__attribute__((address_space(3))) unsigned int*)(&sK[buf][8 * cc][0]),
          16, 0, 0);
    }
  };
  auto stageV = [&](int t, int buf) {
#pragma unroll
    for (int c = 0; c < 2; ++c) {
      const int cc   = 2 * w + c;
      const int dsrc = 8 * cc + (lane >> 3);
      const int blk  = (lane & 7) ^ ((dsrc ^ (dsrc >> 3)) & 7);
      __builtin_amdgcn_global_load_lds(
          (const __attribute__((address_space(1))) unsigned int*)(
              VT + vtb + (size_t)dsrc * SEQ + t * KB + blk * 8),
          (__attribute__((address_space(3))) unsigned int*)(&sVT[buf][8 * cc][0]),
          16, 0, 0);
    }
  };

#pragma unroll 1
  for (int phase = 0; phase < 2; ++phase) {
    const int qtile = phase == 0 ? pairb : (NQT - 1 - pairb);
    const int qwave = qtile * QB + w * 16;   // wave's 16 q-rows
    const int T     = qtile + 1;             // KV 64-tiles this phase

    bf16x8 qf[2];
    {
      const int qrow = qwave + l15;
#pragma unroll
      for (int kk = 0; kk < 2; ++kk)
        qf[kk] = *(const bf16x8*)&Z2[zb2 + (size_t)qrow * E2 + qcol0 + kk * 32 + lhi * 8];
    }

    f32x4 accO[4];
    f32x4 accL;
#pragma unroll
    for (int dt = 0; dt < 4; ++dt) accO[dt] = z4;
    accL = z4;

    stageK(0, 0);
    stageV(0, 0);
    __syncthreads();

#pragma unroll 1
    for (int t = 0; t < T; ++t) {
      const int cur = t & 1;
      if (t + 1 < T) { stageK(t + 1, cur ^ 1); stageV(t + 1, cur ^ 1); }

      f32x4 st[4];
      __builtin_amdgcn_s_setprio(1);
#pragma unroll
      for (int kt = 0; kt < 4; ++kt) {
        const int blk0 = (lhi ^ l7) * 8;
        const int blk1 = ((4 + lhi) ^ l7) * 8;
        bf16x8 kf0 = *(const bf16x8*)&sK[cur][kt * 16 + l15][blk0];
        st[kt] = __builtin_amdgcn_mfma_f32_16x16x32_bf16(kf0, qf[0], z4, 0, 0, 0);
        bf16x8 kf1 = *(const bf16x8*)&sK[cur][kt * 16 + l15][blk1];
        st[kt] = __builtin_amdgcn_mfma_f32_16x16x32_bf16(kf1, qf[1], st[kt], 0, 0, 0);
      }
      __builtin_amdgcn_s_setprio(0);

      if (t == T - 1) {
#pragma unroll
        for (int kt = 0; kt < 4; ++kt) {
          if (kt > w) st[kt] = neg4;
          else if (kt == w) {
#pragma unroll
            for (int r = 0; r < 4; ++r)
              if (lhi * 4 + r > l15) st[kt][r] = -1e32f;
          }
        }
      }

      bf16x8 pb[2];
#pragma unroll
      for (int c = 0; c < 2; ++c) {
        u32x4 pu;
#pragma unroll
        for (int i = 0; i < 4; ++i) {
          const int kt = 2 * c + (i >> 1);
          const int r  = (2 * i) & 3;
          const float p0 = exp2f(st[kt][r]);
          const float p1 = exp2f(st[kt][r + 1]);
          const bf16 b0v = (bf16)p0;
          const bf16 b1v = (bf16)p1;
          pu[i] = (unsigned int)__builtin_bit_cast(unsigned short, b0v)
                | ((unsigned int)__builtin_bit_cast(unsigned short, b1v) << 16);
        }
        pb[c] = __builtin_bit_cast(bf16x8, pu);
      }

      __builtin_amdgcn_s_setprio(1);
#pragma unroll
      for (int c = 0; c < 2; ++c)
        accL = __builtin_amdgcn_mfma_f32_16x16x32_bf16(onesf, pb[c], accL, 0, 0, 0);

#pragma unroll
      for (int c = 0; c < 2; ++c) {
#pragma unroll
        for (int dt = 0; dt < 4; ++dt) {
          const int idxv = ((4 * c + lhi) ^ (l7 ^ ((2 * dt + e2) & 7))) << 3;
          const bf16x8 av = *(const bf16x8*)&sVT[cur][dt * 16 + l15][idxv];
          accO[dt] = __builtin_amdgcn_mfma_f32_16x16x32_bf16(av, pb[c], accO[dt], 0, 0, 0);
        }
      }
      __builtin_amdgcn_s_setprio(0);

      __syncthreads();
    }

    {
      const float inv  = 1.f / accL[0];
      const int   qrow = qwave + l15;
#pragma unroll
      for (int dt = 0; dt < 4; ++dt) {
        float4 o;
        o.x = accO[dt][0] * inv;
        o.y = accO[dt][1] * inv;
        o.z = accO[dt][2] * inv;
        o.w = accO[dt][3] * inv;
        *(float4*)&out[ob + (size_t)qrow * DM + h * HD + dt * 16 + lhi * 4] = o;
      }
    }
  }
}

extern "C" void kernel_launch(void* const* d_in, const int* in_sizes, int n_in,
                              void* d_out, int out_size, void* d_ws, size_t ws_size,
                              hipStream_t stream) {
  const float* x    = (const float*)d_in[0];
  const float* W    = (const float*)d_in[1];
  const float* bias = (const float*)d_in[2];
  float* out = (float*)d_out;

  // workspace: xb 16MB | Wb 6MB | Z2 32MB | VT 16MB  (= 70MB)
  bf16* xb = (bf16*)d_ws;
  bf16* Wb = xb + (size_t)NBAT * SEQ * DM;
  bf16* Z2 = Wb + (size_t)E3 * DM;
  bf16* VT = Z2 + (size_t)NBAT * SEQ * E2;

  cvt2_bf16_kernel<<<1536, 256, 0, stream>>>(x, xb, NBAT * SEQ * DM / 8,
                                             W, Wb, E3 * DM / 8);

  qkv_gemm_kernel<<<1536, 256, 0, stream>>>(xb, Wb, bias, Z2, VT);  // XCD-chunked

  attn_kernel<<<1024, 256, 0, stream>>>(Z2, VT, out);   // uniform, 4/CU
}

// Round 26
// 147.762 us; speedup vs baseline: 1.0655x; 1.0655x over previous
//
#include <hip/hip_runtime.h>
#include <hip/hip_bf16.h>

typedef __bf16 bf16;
typedef __bf16 bf16x4 __attribute__((ext_vector_type(4)));
typedef __bf16 bf16x8 __attribute__((ext_vector_type(8)));
typedef float f32x4 __attribute__((ext_vector_type(4)));
typedef unsigned int u32x4 __attribute__((ext_vector_type(4)));

#define SEQ   2048
#define NBAT  4
#define DM    1024
#define NH    16
#define HD    64
#define E3    3072
#define E2    2048   // Z2 row stride: [K(0:1024) | Q_scaled(1024:2048)]

#define SL2E_C 0.04508422f   // (1/32) * log2(e)

// ---------------- fp32 -> bf16 convert (x and W fused in one launch) ----------------
__global__ void cvt2_bf16_kernel(const float* __restrict__ a, bf16* __restrict__ oa, int na8,
                                 const float* __restrict__ b, bf16* __restrict__ ob, int nb8) {
  const int stride = gridDim.x * blockDim.x;
  const int ntot = na8 + nb8;
  for (int i = blockIdx.x * blockDim.x + threadIdx.x; i < ntot; i += stride) {
    const float* src;
    bf16* dst;
    int j;
    if (i < na8) { src = a; dst = oa; j = i; }
    else         { src = b; dst = ob; j = i - na8; }
    const float4* p = (const float4*)(src + (size_t)j * 8);
    float4 x = p[0];
    float4 y = p[1];
    bf16x8 o;
    o[0] = (bf16)x.x; o[1] = (bf16)x.y; o[2] = (bf16)x.z; o[3] = (bf16)x.w;
    o[4] = (bf16)y.x; o[5] = (bf16)y.y; o[6] = (bf16)y.z; o[7] = (bf16)y.w;
    *(bf16x8*)(dst + (size_t)j * 8) = o;
  }
}

// ---------------- QKV projection GEMM ----------------
// 2D grid (r24 decode — r25's XCD-chunking regressed: A streamed 8x).
// r26: LDS XOR-block swizzle on sA/sB (T2). Stored 16B block = content
// block ^ ((row>>1)&3), applied by pre-swizzling the per-lane GLOBAL source
// (skk) while the LDS dest stays linear (rule #21); fragment reads XOR the
// same term. Was an 8-way conflict on every A/B fragment read (6.3e6
// SQ_LDS_BANK_CONFLICT); now 2-way = free.
// K cols -> Z2 row-major; Q cols pre-scaled by scale*log2e; V cols ->
// sigma-permuted transposed VT (b64 stores).
#define BM 128
#define BN 128
#define BK 32
#define KSTEPS (DM / BK)

__global__ __launch_bounds__(256, 2) void qkv_gemm_kernel(
    const bf16* __restrict__ A, const bf16* __restrict__ B,
    const float* __restrict__ bias, bf16* __restrict__ Z2, bf16* __restrict__ VT)
{
  __shared__ bf16 sA[2][BM * BK];
  __shared__ bf16 sB[2][BN * BK];

  const int tid  = threadIdx.x;
  const int lane = tid & 63;
  const int w    = tid >> 6;
  const int wr   = w >> 1;
  const int wc   = w & 1;
  const int m0   = blockIdx.x * BM;
  const int n0   = blockIdx.y * BN;

  const f32x4 z4 = {0.f, 0.f, 0.f, 0.f};
  f32x4 acc[4][4];
#pragma unroll
  for (int i = 0; i < 4; ++i)
#pragma unroll
    for (int j = 0; j < 4; ++j)
      acc[i][j] = z4;

  const int srow = w * 32 + (lane >> 2);
  // source pre-swizzle: stored block (lane&3) holds content block
  // (lane&3) ^ s(row), s(row) = (row>>1)&3 = (lane>>3)&3 within the chunk
  const int skk  = ((lane & 3) ^ ((lane >> 3) & 3)) * 8;
  const bf16* gA = A + (size_t)m0 * DM;
  const bf16* gB = B + (size_t)n0 * DM;

  auto stage = [&](int buf, int t) {
    const int k0 = t * BK;
#pragma unroll
    for (int c = 0; c < 2; ++c)
      __builtin_amdgcn_global_load_lds(
          (const __attribute__((address_space(1))) unsigned int*)(gA + (size_t)(srow + c * 16) * DM + k0 + skk),
          (__attribute__((address_space(3))) unsigned int*)(&sA[buf][w * 1024 + c * 512]),
          16, 0, 0);
#pragma unroll
    for (int c = 0; c < 2; ++c)
      __builtin_amdgcn_global_load_lds(
          (const __attribute__((address_space(1))) unsigned int*)(gB + (size_t)(srow + c * 16) * DM + k0 + skk),
          (__attribute__((address_space(3))) unsigned int*)(&sB[buf][w * 1024 + c * 512]),
          16, 0, 0);
  };

  stage(0, 0);
  int cur = 0;
  const int arow = wr * 64 + (lane & 15);
  const int brow = wc * 64 + (lane & 15);
  // fragment read block: content block lhi at stored block lhi ^ s(row);
  // s(row) = ((lane&15)>>1)&3 (the +i*16 / +64 row terms don't touch bits 1-2)
  const int kf   = (((lane >> 4) ^ (((lane & 15) >> 1) & 3)) & 3) * 8;

  for (int t = 0; t < KSTEPS; ++t) {
    __syncthreads();
    if (t + 1 < KSTEPS) stage(cur ^ 1, t + 1);
    bf16x8 af[4], bfr[4];
#pragma unroll
    for (int i = 0; i < 4; ++i)
      af[i] = *(const bf16x8*)&sA[cur][(arow + i * 16) * BK + kf];
#pragma unroll
    for (int j = 0; j < 4; ++j)
      bfr[j] = *(const bf16x8*)&sB[cur][(brow + j * 16) * BK + kf];
#pragma unroll
    for (int i = 0; i < 4; ++i)
#pragma unroll
      for (int j = 0; j < 4; ++j)
        acc[i][j] = __builtin_amdgcn_mfma_f32_16x16x32_bf16(af[i], bfr[j], acc[i][j], 0, 0, 0);
    cur ^= 1;
  }

  if (n0 < 2048) {
    // K/Q block: row-major Z2; Q columns pre-scaled by scale*log2e (fp32)
    const float sc = (n0 >= 1024) ? SL2E_C : 1.0f;
#pragma unroll
    for (int i = 0; i < 4; ++i) {
#pragma unroll
      for (int j = 0; j < 4; ++j) {
        const int col = n0 + wc * 64 + j * 16 + (lane & 15);
        const float bb = bias[col];
#pragma unroll
        for (int r = 0; r < 4; ++r) {
          const int row = m0 + wr * 64 + i * 16 + (lane >> 4) * 4 + r;
          Z2[(size_t)row * E2 + col] = (bf16)((acc[i][j][r] + bb) * sc);
        }
      }
    }
  } else {
    // V block: transposed, sigma-permuted VT[n][h][d][k'] (b64 stores)
#pragma unroll
    for (int i = 0; i < 4; ++i) {
      const int rowb = m0 + wr * 64 + i * 16 + (lane >> 4) * 4;
      const int nb   = rowb >> 11;
      const int k    = rowb & 2047;
      const int ksig = (k & ~63) | (k & 32) | (((k >> 2) & 3) << 3) | (((k >> 4) & 1) << 2);
#pragma unroll
      for (int j = 0; j < 4; ++j) {
        const int col  = n0 + wc * 64 + j * 16 + (lane & 15);
        const float bb = bias[col];
        const int colv = col - 2048;
        const int h    = colv >> 6;
        const int d    = colv & 63;
        bf16x4 v4;
#pragma unroll
        for (int r = 0; r < 4; ++r) v4[r] = (bf16)(acc[i][j][r] + bb);
        *(bf16x4*)&VT[(((size_t)nb * NH + h) * HD + d) * SEQ + ksig] = v4;
      }
    }
  }
}

// ---------------- causal flash attention ----------------
// r24 champion body, unchanged: QB = KB = 64, 4 waves x 16 q-rows, 32 qtiles
// pair-scheduled (b, 31-b) -> 1024 UNIFORM blocks, 4/CU. XCD-local remap.
// Swapped QK^T, NO-MAX softmax (scale folded into Q by the GEMM), ones-MFMA
// denominator, all-DMA K/V staging, sigma-contiguous b128 sVT reads.
#define QB 64
#define KB 64
#define NQT (SEQ / QB)   // 32

__global__ __launch_bounds__(256, 4) void attn_kernel(
    const bf16* __restrict__ Z2, const bf16* __restrict__ VT, float* __restrict__ out)
{
  __shared__ bf16 sK[2][KB][64];    // [buf][k][swizzled d]    16 KB
  __shared__ bf16 sVT[2][HD][64];   // [buf][d][sigma(k)^X(d)] 16 KB

  const int tid   = threadIdx.x;
  const int lane  = tid & 63;
  const int w     = tid >> 6;        // 0..3
  const int l15   = lane & 15;
  const int lhi   = lane >> 4;
  const int l7    = l15 & 7;
  const int e2    = l15 >> 3;        // 0/1

  const int flat  = blockIdx.x;
  const int xcd   = flat & 7;
  const int u     = flat >> 3;          // 0..127
  const int ctx   = xcd * 8 + (u & 7);
  const int pairb = u >> 3;             // 0..15
  const int h     = ctx & 15;
  const int n     = ctx >> 4;

  const size_t zb2 = (size_t)n * SEQ * E2;
  const size_t vtb = ((size_t)n * NH + h) * HD * SEQ;
  const int kcol0 = h * HD;
  const int qcol0 = DM + h * HD;

  const f32x4 z4 = {0.f, 0.f, 0.f, 0.f};
  const f32x4 neg4 = {-1e32f, -1e32f, -1e32f, -1e32f};

  const u32x4 onesu = {0x3F803F80u, 0x3F803F80u, 0x3F803F80u, 0x3F803F80u};
  const bf16x8 onesf = __builtin_bit_cast(bf16x8, onesu);

  const int krow_in = lane >> 3;                        // 0..7 within chunk
  const int kdblk   = ((lane & 7) ^ (lane >> 3)) * 8;   // swizzled d offset

  const size_t ob = (size_t)n * SEQ * DM;

  auto stageK = [&](int t, int buf) {
#pragma unroll
    for (int c = 0; c < 2; ++c) {
      const int cc = 2 * w + c;
      __builtin_amdgcn_global_load_lds(
          (const __attribute__((address_space(1))) unsigned int*)(
              Z2 + zb2 + (size_t)(t * KB + 8 * cc + krow_in) * E2 + kcol0 + kdblk),
          (__attribute__((address_space(3))) unsigned int*)(&sK[buf][8 * cc][0]),
          16, 0, 0);
    }
  };
  auto stageV = [&](int t, int buf) {
#pragma unroll
    for (int c = 0; c < 2; ++c) {
      const int cc   = 2 * w + c;
      const int dsrc = 8 * cc + (lane >> 3);
      const int blk  = (lane & 7) ^ ((dsrc ^ (dsrc >> 3)) & 7);
      __builtin_amdgcn_global_load_lds(
          (const __attribute__((address_space(1))) unsigned int*)(
              VT + vtb + (size_t)dsrc * SEQ + t * KB + blk * 8),
          (__attribute__((address_space(3))) unsigned int*)(&sVT[buf][8 * cc][0]),
          16, 0, 0);
    }
  };

#pragma unroll 1
  for (int phase = 0; phase < 2; ++phase) {
    const int qtile = phase == 0 ? pairb : (NQT - 1 - pairb);
    const int qwave = qtile * QB + w * 16;   // wave's 16 q-rows
    const int T     = qtile + 1;             // KV 64-tiles this phase

    bf16x8 qf[2];
    {
      const int qrow = qwave + l15;
#pragma unroll
      for (int kk = 0; kk < 2; ++kk)
        qf[kk] = *(const bf16x8*)&Z2[zb2 + (size_t)qrow * E2 + qcol0 + kk * 32 + lhi * 8];
    }

    f32x4 accO[4];
    f32x4 accL;
#pragma unroll
    for (int dt = 0; dt < 4; ++dt) accO[dt] = z4;
    accL = z4;

    stageK(0, 0);
    stageV(0, 0);
    __syncthreads();

#pragma unroll 1
    for (int t = 0; t < T; ++t) {
      const int cur = t & 1;
      if (t + 1 < T) { stageK(t + 1, cur ^ 1); stageV(t + 1, cur ^ 1); }

      f32x4 st[4];
      __builtin_amdgcn_s_setprio(1);
#pragma unroll
      for (int kt = 0; kt < 4; ++kt) {
        const int blk0 = (lhi ^ l7) * 8;
        const int blk1 = ((4 + lhi) ^ l7) * 8;
        bf16x8 kf0 = *(const bf16x8*)&sK[cur][kt * 16 + l15][blk0];
        st[kt] = __builtin_amdgcn_mfma_f32_16x16x32_bf16(kf0, qf[0], z4, 0, 0, 0);
        bf16x8 kf1 = *(const bf16x8*)&sK[cur][kt * 16 + l15][blk1];
        st[kt] = __builtin_amdgcn_mfma_f32_16x16x32_bf16(kf1, qf[1], st[kt], 0, 0, 0);
      }
      __builtin_amdgcn_s_setprio(0);

      if (t == T - 1) {
#pragma unroll
        for (int kt = 0; kt < 4; ++kt) {
          if (kt > w) st[kt] = neg4;
          else if (kt == w) {
#pragma unroll
            for (int r = 0; r < 4; ++r)
              if (lhi * 4 + r > l15) st[kt][r] = -1e32f;
          }
        }
      }

      bf16x8 pb[2];
#pragma unroll
      for (int c = 0; c < 2; ++c) {
        u32x4 pu;
#pragma unroll
        for (int i = 0; i < 4; ++i) {
          const int kt = 2 * c + (i >> 1);
          const int r  = (2 * i) & 3;
          const float p0 = exp2f(st[kt][r]);
          const float p1 = exp2f(st[kt][r + 1]);
          const bf16 b0v = (bf16)p0;
          const bf16 b1v = (bf16)p1;
          pu[i] = (unsigned int)__builtin_bit_cast(unsigned short, b0v)
                | ((unsigned int)__builtin_bit_cast(unsigned short, b1v) << 16);
        }
        pb[c] = __builtin_bit_cast(bf16x8, pu);
      }

      __builtin_amdgcn_s_setprio(1);
#pragma unroll
      for (int c = 0; c < 2; ++c)
        accL = __builtin_amdgcn_mfma_f32_16x16x32_bf16(onesf, pb[c], accL, 0, 0, 0);

#pragma unroll
      for (int c = 0; c < 2; ++c) {
#pragma unroll
        for (int dt = 0; dt < 4; ++dt) {
          const int idxv = ((4 * c + lhi) ^ (l7 ^ ((2 * dt + e2) & 7))) << 3;
          const bf16x8 av = *(const bf16x8*)&sVT[cur][dt * 16 + l15][idxv];
          accO[dt] = __builtin_amdgcn_mfma_f32_16x16x32_bf16(av, pb[c], accO[dt], 0, 0, 0);
        }
      }
      __builtin_amdgcn_s_setprio(0);

      __syncthreads();
    }

    {
      const float inv  = 1.f / accL[0];
      const int   qrow = qwave + l15;
#pragma unroll
      for (int dt = 0; dt < 4; ++dt) {
        float4 o;
        o.x = accO[dt][0] * inv;
        o.y = accO[dt][1] * inv;
        o.z = accO[dt][2] * inv;
        o.w = accO[dt][3] * inv;
        *(float4*)&out[ob + (size_t)qrow * DM + h * HD + dt * 16 + lhi * 4] = o;
      }
    }
  }
}

extern "C" void kernel_launch(void* const* d_in, const int* in_sizes, int n_in,
                              void* d_out, int out_size, void* d_ws, size_t ws_size,
                              hipStream_t stream) {
  const float* x    = (const float*)d_in[0];
  const float* W    = (const float*)d_in[1];
  const float* bias = (const float*)d_in[2];
  float* out = (float*)d_out;

  // workspace: xb 16MB | Wb 6MB | Z2 32MB | VT 16MB  (= 70MB)
  bf16* xb = (bf16*)d_ws;
  bf16* Wb = xb + (size_t)NBAT * SEQ * DM;
  bf16* Z2 = Wb + (size_t)E3 * DM;
  bf16* VT = Z2 + (size_t)NBAT * SEQ * E2;

  cvt2_bf16_kernel<<<1536, 256, 0, stream>>>(x, xb, NBAT * SEQ * DM / 8,
                                             W, Wb, E3 * DM / 8);

  dim3 g1(NBAT * SEQ / BM, E3 / BN);
  qkv_gemm_kernel<<<g1, 256, 0, stream>>>(xb, Wb, bias, Z2, VT);  // 2D grid (revert)

  attn_kernel<<<1024, 256, 0, stream>>>(Z2, VT, out);   // uniform, 4/CU
}

// Round 27
// 132.625 us; speedup vs baseline: 1.1871x; 1.1141x over previous
//
#include <hip/hip_runtime.h>
#include <hip/hip_bf16.h>

typedef __bf16 bf16;
typedef __bf16 bf16x4 __attribute__((ext_vector_type(4)));
typedef __bf16 bf16x8 __attribute__((ext_vector_type(8)));
typedef float f32x4 __attribute__((ext_vector_type(4)));
typedef unsigned int u32x4 __attribute__((ext_vector_type(4)));

#define SEQ   2048
#define NBAT  4
#define DM    1024
#define NH    16
#define HD    64
#define E3    3072
#define E2    2048   // Z2 row stride: [K(0:1024) | Q_scaled(1024:2048)]

#define SL2E_C 0.04508422f   // (1/32) * log2(e)

// ---------------- fp32 -> bf16 convert (x and W fused in one launch) ----------------
__global__ void cvt2_bf16_kernel(const float* __restrict__ a, bf16* __restrict__ oa, int na8,
                                 const float* __restrict__ b, bf16* __restrict__ ob, int nb8) {
  const int stride = gridDim.x * blockDim.x;
  const int ntot = na8 + nb8;
  for (int i = blockIdx.x * blockDim.x + threadIdx.x; i < ntot; i += stride) {
    const float* src;
    bf16* dst;
    int j;
    if (i < na8) { src = a; dst = oa; j = i; }
    else         { src = b; dst = ob; j = i - na8; }
    const float4* p = (const float4*)(src + (size_t)j * 8);
    float4 x = p[0];
    float4 y = p[1];
    bf16x8 o;
    o[0] = (bf16)x.x; o[1] = (bf16)x.y; o[2] = (bf16)x.z; o[3] = (bf16)x.w;
    o[4] = (bf16)y.x; o[5] = (bf16)y.y; o[6] = (bf16)y.z; o[7] = (bf16)y.w;
    *(bf16x8*)(dst + (size_t)j * 8) = o;
  }
}

// ---------------- QKV projection GEMM ----------------
// 2D grid; LDS XOR-block swizzle on sA/sB (r26, neutral but conflict-free).
// K cols -> Z2 row-major; Q cols pre-scaled by scale*log2e; V cols ->
// sigma-permuted transposed VT (b64 stores).
#define BM 128
#define BN 128
#define BK 32
#define KSTEPS (DM / BK)

__global__ __launch_bounds__(256, 2) void qkv_gemm_kernel(
    const bf16* __restrict__ A, const bf16* __restrict__ B,
    const float* __restrict__ bias, bf16* __restrict__ Z2, bf16* __restrict__ VT)
{
  __shared__ bf16 sA[2][BM * BK];
  __shared__ bf16 sB[2][BN * BK];

  const int tid  = threadIdx.x;
  const int lane = tid & 63;
  const int w    = tid >> 6;
  const int wr   = w >> 1;
  const int wc   = w & 1;
  const int m0   = blockIdx.x * BM;
  const int n0   = blockIdx.y * BN;

  const f32x4 z4 = {0.f, 0.f, 0.f, 0.f};
  f32x4 acc[4][4];
#pragma unroll
  for (int i = 0; i < 4; ++i)
#pragma unroll
    for (int j = 0; j < 4; ++j)
      acc[i][j] = z4;

  const int srow = w * 32 + (lane >> 2);
  const int skk  = ((lane & 3) ^ ((lane >> 3) & 3)) * 8;   // source pre-swizzle
  const bf16* gA = A + (size_t)m0 * DM;
  const bf16* gB = B + (size_t)n0 * DM;

  auto stage = [&](int buf, int t) {
    const int k0 = t * BK;
#pragma unroll
    for (int c = 0; c < 2; ++c)
      __builtin_amdgcn_global_load_lds(
          (const __attribute__((address_space(1))) unsigned int*)(gA + (size_t)(srow + c * 16) * DM + k0 + skk),
          (__attribute__((address_space(3))) unsigned int*)(&sA[buf][w * 1024 + c * 512]),
          16, 0, 0);
#pragma unroll
    for (int c = 0; c < 2; ++c)
      __builtin_amdgcn_global_load_lds(
          (const __attribute__((address_space(1))) unsigned int*)(gB + (size_t)(srow + c * 16) * DM + k0 + skk),
          (__attribute__((address_space(3))) unsigned int*)(&sB[buf][w * 1024 + c * 512]),
          16, 0, 0);
  };

  stage(0, 0);
  int cur = 0;
  const int arow = wr * 64 + (lane & 15);
  const int brow = wc * 64 + (lane & 15);
  const int kf   = (((lane >> 4) ^ (((lane & 15) >> 1) & 3)) & 3) * 8;  // read-side XOR

  for (int t = 0; t < KSTEPS; ++t) {
    __syncthreads();
    if (t + 1 < KSTEPS) stage(cur ^ 1, t + 1);
    bf16x8 af[4], bfr[4];
#pragma unroll
    for (int i = 0; i < 4; ++i)
      af[i] = *(const bf16x8*)&sA[cur][(arow + i * 16) * BK + kf];
#pragma unroll
    for (int j = 0; j < 4; ++j)
      bfr[j] = *(const bf16x8*)&sB[cur][(brow + j * 16) * BK + kf];
#pragma unroll
    for (int i = 0; i < 4; ++i)
#pragma unroll
      for (int j = 0; j < 4; ++j)
        acc[i][j] = __builtin_amdgcn_mfma_f32_16x16x32_bf16(af[i], bfr[j], acc[i][j], 0, 0, 0);
    cur ^= 1;
  }

  if (n0 < 2048) {
    // K/Q block: row-major Z2; Q columns pre-scaled by scale*log2e (fp32)
    const float sc = (n0 >= 1024) ? SL2E_C : 1.0f;
#pragma unroll
    for (int i = 0; i < 4; ++i) {
#pragma unroll
      for (int j = 0; j < 4; ++j) {
        const int col = n0 + wc * 64 + j * 16 + (lane & 15);
        const float bb = bias[col];
#pragma unroll
        for (int r = 0; r < 4; ++r) {
          const int row = m0 + wr * 64 + i * 16 + (lane >> 4) * 4 + r;
          Z2[(size_t)row * E2 + col] = (bf16)((acc[i][j][r] + bb) * sc);
        }
      }
    }
  } else {
    // V block: transposed, sigma-permuted VT[n][h][d][k'] (b64 stores)
#pragma unroll
    for (int i = 0; i < 4; ++i) {
      const int rowb = m0 + wr * 64 + i * 16 + (lane >> 4) * 4;
      const int nb   = rowb >> 11;
      const int k    = rowb & 2047;
      const int ksig = (k & ~63) | (k & 32) | (((k >> 2) & 3) << 3) | (((k >> 4) & 1) << 2);
#pragma unroll
      for (int j = 0; j < 4; ++j) {
        const int col  = n0 + wc * 64 + j * 16 + (lane & 15);
        const float bb = bias[col];
        const int colv = col - 2048;
        const int h    = colv >> 6;
        const int d    = colv & 63;
        bf16x4 v4;
#pragma unroll
        for (int r = 0; r < 4; ++r) v4[r] = (bf16)(acc[i][j][r] + bb);
        *(bf16x4*)&VT[(((size_t)nb * NH + h) * HD + d) * SEQ + ksig] = v4;
      }
    }
  }
}

// ---------------- causal flash attention ----------------
// r24/r26 champion body with ONE change: exp2f -> __builtin_amdgcn_exp2f
// (raw v_exp_f32; libm exp2f expands a guarded sequence x16 per tile —
// args are bounded, masked lanes (-1e32) give exactly 0).
#define QB 64
#define KB 64
#define NQT (SEQ / QB)   // 32

__global__ __launch_bounds__(256, 4) void attn_kernel(
    const bf16* __restrict__ Z2, const bf16* __restrict__ VT, float* __restrict__ out)
{
  __shared__ bf16 sK[2][KB][64];    // [buf][k][swizzled d]    16 KB
  __shared__ bf16 sVT[2][HD][64];   // [buf][d][sigma(k)^X(d)] 16 KB

  const int tid   = threadIdx.x;
  const int lane  = tid & 63;
  const int w     = tid >> 6;        // 0..3
  const int l15   = lane & 15;
  const int lhi   = lane >> 4;
  const int l7    = l15 & 7;
  const int e2    = l15 >> 3;        // 0/1

  const int flat  = blockIdx.x;
  const int xcd   = flat & 7;
  const int u     = flat >> 3;          // 0..127
  const int ctx   = xcd * 8 + (u & 7);
  const int pairb = u >> 3;             // 0..15
  const int h     = ctx & 15;
  const int n     = ctx >> 4;

  const size_t zb2 = (size_t)n * SEQ * E2;
  const size_t vtb = ((size_t)n * NH + h) * HD * SEQ;
  const int kcol0 = h * HD;
  const int qcol0 = DM + h * HD;

  const f32x4 z4 = {0.f, 0.f, 0.f, 0.f};
  const f32x4 neg4 = {-1e32f, -1e32f, -1e32f, -1e32f};

  const u32x4 onesu = {0x3F803F80u, 0x3F803F80u, 0x3F803F80u, 0x3F803F80u};
  const bf16x8 onesf = __builtin_bit_cast(bf16x8, onesu);

  const int krow_in = lane >> 3;                        // 0..7 within chunk
  const int kdblk   = ((lane & 7) ^ (lane >> 3)) * 8;   // swizzled d offset

  const size_t ob = (size_t)n * SEQ * DM;

  auto stageK = [&](int t, int buf) {
#pragma unroll
    for (int c = 0; c < 2; ++c) {
      const int cc = 2 * w + c;
      __builtin_amdgcn_global_load_lds(
          (const __attribute__((address_space(1))) unsigned int*)(
              Z2 + zb2 + (size_t)(t * KB + 8 * cc + krow_in) * E2 + kcol0 + kdblk),
          (__attribute__((address_space(3))) unsigned int*)(&sK[buf][8 * cc][0]),
          16, 0, 0);
    }
  };
  auto stageV = [&](int t, int buf) {
#pragma unroll
    for (int c = 0; c < 2; ++c) {
      const int cc   = 2 * w + c;
      const int dsrc = 8 * cc + (lane >> 3);
      const int blk  = (lane & 7) ^ ((dsrc ^ (dsrc >> 3)) & 7);
      __builtin_amdgcn_global_load_lds(
          (const __attribute__((address_space(1))) unsigned int*)(
              VT + vtb + (size_t)dsrc * SEQ + t * KB + blk * 8),
          (__attribute__((address_space(3))) unsigned int*)(&sVT[buf][8 * cc][0]),
          16, 0, 0);
    }
  };

#pragma unroll 1
  for (int phase = 0; phase < 2; ++phase) {
    const int qtile = phase == 0 ? pairb : (NQT - 1 - pairb);
    const int qwave = qtile * QB + w * 16;   // wave's 16 q-rows
    const int T     = qtile + 1;             // KV 64-tiles this phase

    bf16x8 qf[2];
    {
      const int qrow = qwave + l15;
#pragma unroll
      for (int kk = 0; kk < 2; ++kk)
        qf[kk] = *(const bf16x8*)&Z2[zb2 + (size_t)qrow * E2 + qcol0 + kk * 32 + lhi * 8];
    }

    f32x4 accO[4];
    f32x4 accL;
#pragma unroll
    for (int dt = 0; dt < 4; ++dt) accO[dt] = z4;
    accL = z4;

    stageK(0, 0);
    stageV(0, 0);
    __syncthreads();

#pragma unroll 1
    for (int t = 0; t < T; ++t) {
      const int cur = t & 1;
      if (t + 1 < T) { stageK(t + 1, cur ^ 1); stageV(t + 1, cur ^ 1); }

      f32x4 st[4];
      __builtin_amdgcn_s_setprio(1);
#pragma unroll
      for (int kt = 0; kt < 4; ++kt) {
        const int blk0 = (lhi ^ l7) * 8;
        const int blk1 = ((4 + lhi) ^ l7) * 8;
        bf16x8 kf0 = *(const bf16x8*)&sK[cur][kt * 16 + l15][blk0];
        st[kt] = __builtin_amdgcn_mfma_f32_16x16x32_bf16(kf0, qf[0], z4, 0, 0, 0);
        bf16x8 kf1 = *(const bf16x8*)&sK[cur][kt * 16 + l15][blk1];
        st[kt] = __builtin_amdgcn_mfma_f32_16x16x32_bf16(kf1, qf[1], st[kt], 0, 0, 0);
      }
      __builtin_amdgcn_s_setprio(0);

      if (t == T - 1) {
#pragma unroll
        for (int kt = 0; kt < 4; ++kt) {
          if (kt > w) st[kt] = neg4;
          else if (kt == w) {
#pragma unroll
            for (int r = 0; r < 4; ++r)
              if (lhi * 4 + r > l15) st[kt][r] = -1e32f;
          }
        }
      }

      // NO-MAX softmax, raw v_exp_f32 (args bounded; masked -> exactly 0)
      bf16x8 pb[2];
#pragma unroll
      for (int c = 0; c < 2; ++c) {
        u32x4 pu;
#pragma unroll
        for (int i = 0; i < 4; ++i) {
          const int kt = 2 * c + (i >> 1);
          const int r  = (2 * i) & 3;
          const float p0 = __builtin_amdgcn_exp2f(st[kt][r]);
          const float p1 = __builtin_amdgcn_exp2f(st[kt][r + 1]);
          const bf16 b0v = (bf16)p0;
          const bf16 b1v = (bf16)p1;
          pu[i] = (unsigned int)__builtin_bit_cast(unsigned short, b0v)
                | ((unsigned int)__builtin_bit_cast(unsigned short, b1v) << 16);
        }
        pb[c] = __builtin_bit_cast(bf16x8, pu);
      }

      __builtin_amdgcn_s_setprio(1);
#pragma unroll
      for (int c = 0; c < 2; ++c)
        accL = __builtin_amdgcn_mfma_f32_16x16x32_bf16(onesf, pb[c], accL, 0, 0, 0);

#pragma unroll
      for (int c = 0; c < 2; ++c) {
#pragma unroll
        for (int dt = 0; dt < 4; ++dt) {
          const int idxv = ((4 * c + lhi) ^ (l7 ^ ((2 * dt + e2) & 7))) << 3;
          const bf16x8 av = *(const bf16x8*)&sVT[cur][dt * 16 + l15][idxv];
          accO[dt] = __builtin_amdgcn_mfma_f32_16x16x32_bf16(av, pb[c], accO[dt], 0, 0, 0);
        }
      }
      __builtin_amdgcn_s_setprio(0);

      __syncthreads();
    }

    {
      const float inv  = 1.f / accL[0];
      const int   qrow = qwave + l15;
#pragma unroll
      for (int dt = 0; dt < 4; ++dt) {
        float4 o;
        o.x = accO[dt][0] * inv;
        o.y = accO[dt][1] * inv;
        o.z = accO[dt][2] * inv;
        o.w = accO[dt][3] * inv;
        *(float4*)&out[ob + (size_t)qrow * DM + h * HD + dt * 16 + lhi * 4] = o;
      }
    }
  }
}

extern "C" void kernel_launch(void* const* d_in, const int* in_sizes, int n_in,
                              void* d_out, int out_size, void* d_ws, size_t ws_size,
                              hipStream_t stream) {
  const float* x    = (const float*)d_in[0];
  const float* W    = (const float*)d_in[1];
  const float* bias = (const float*)d_in[2];
  float* out = (float*)d_out;

  // workspace: xb 16MB | Wb 6MB | Z2 32MB | VT 16MB  (= 70MB)
  bf16* xb = (bf16*)d_ws;
  bf16* Wb = xb + (size_t)NBAT * SEQ * DM;
  bf16* Z2 = Wb + (size_t)E3 * DM;
  bf16* VT = Z2 + (size_t)NBAT * SEQ * E2;

  cvt2_bf16_kernel<<<1536, 256, 0, stream>>>(x, xb, NBAT * SEQ * DM / 8,
                                             W, Wb, E3 * DM / 8);

  dim3 g1(NBAT * SEQ / BM, E3 / BN);
  qkv_gemm_kernel<<<g1, 256, 0, stream>>>(xb, Wb, bias, Z2, VT);

  attn_kernel<<<1024, 256, 0, stream>>>(Z2, VT, out);   // uniform, 4/CU
}

// Round 28
// 132.418 us; speedup vs baseline: 1.1889x; 1.0016x over previous
//
#include <hip/hip_runtime.h>
#include <hip/hip_bf16.h>

typedef __bf16 bf16;
typedef __bf16 bf16x4 __attribute__((ext_vector_type(4)));
typedef __bf16 bf16x8 __attribute__((ext_vector_type(8)));
typedef float f32x4 __attribute__((ext_vector_type(4)));
typedef unsigned int u32x4 __attribute__((ext_vector_type(4)));

#define SEQ   2048
#define NBAT  4
#define DM    1024
#define NH    16
#define HD    64
#define E3    3072
#define E2    2048   // Z2 row stride: [K(0:1024) | Q_scaled(1024:2048)]

#define SL2E_C 0.04508422f   // (1/32) * log2(e)

// ---------------- fp32 -> bf16 convert (x and W fused in one launch) ----------------
__global__ void cvt2_bf16_kernel(const float* __restrict__ a, bf16* __restrict__ oa, int na8,
                                 const float* __restrict__ b, bf16* __restrict__ ob, int nb8) {
  const int stride = gridDim.x * blockDim.x;
  const int ntot = na8 + nb8;
  for (int i = blockIdx.x * blockDim.x + threadIdx.x; i < ntot; i += stride) {
    const float* src;
    bf16* dst;
    int j;
    if (i < na8) { src = a; dst = oa; j = i; }
    else         { src = b; dst = ob; j = i - na8; }
    const float4* p = (const float4*)(src + (size_t)j * 8);
    float4 x = p[0];
    float4 y = p[1];
    bf16x8 o;
    o[0] = (bf16)x.x; o[1] = (bf16)x.y; o[2] = (bf16)x.z; o[3] = (bf16)x.w;
    o[4] = (bf16)y.x; o[5] = (bf16)y.y; o[6] = (bf16)y.z; o[7] = (bf16)y.w;
    *(bf16x8*)(dst + (size_t)j * 8) = o;
  }
}

// ---------------- QKV projection GEMM ----------------
// 2D grid; LDS XOR-block swizzle on sA/sB (conflict-free, r26).
// r28: __launch_bounds__(256,3) — guarantee 3 blocks/CU residency (was
// averaging 2.4 at (256,2); LDS allows 5, regs 120 < 170 cap -> no spill).
// K cols -> Z2 row-major; Q cols pre-scaled by scale*log2e; V cols ->
// sigma-permuted transposed VT (b64 stores).
#define BM 128
#define BN 128
#define BK 32
#define KSTEPS (DM / BK)

__global__ __launch_bounds__(256, 3) void qkv_gemm_kernel(
    const bf16* __restrict__ A, const bf16* __restrict__ B,
    const float* __restrict__ bias, bf16* __restrict__ Z2, bf16* __restrict__ VT)
{
  __shared__ bf16 sA[2][BM * BK];
  __shared__ bf16 sB[2][BN * BK];

  const int tid  = threadIdx.x;
  const int lane = tid & 63;
  const int w    = tid >> 6;
  const int wr   = w >> 1;
  const int wc   = w & 1;
  const int m0   = blockIdx.x * BM;
  const int n0   = blockIdx.y * BN;

  const f32x4 z4 = {0.f, 0.f, 0.f, 0.f};
  f32x4 acc[4][4];
#pragma unroll
  for (int i = 0; i < 4; ++i)
#pragma unroll
    for (int j = 0; j < 4; ++j)
      acc[i][j] = z4;

  const int srow = w * 32 + (lane >> 2);
  const int skk  = ((lane & 3) ^ ((lane >> 3) & 3)) * 8;   // source pre-swizzle
  const bf16* gA = A + (size_t)m0 * DM;
  const bf16* gB = B + (size_t)n0 * DM;

  auto stage = [&](int buf, int t) {
    const int k0 = t * BK;
#pragma unroll
    for (int c = 0; c < 2; ++c)
      __builtin_amdgcn_global_load_lds(
          (const __attribute__((address_space(1))) unsigned int*)(gA + (size_t)(srow + c * 16) * DM + k0 + skk),
          (__attribute__((address_space(3))) unsigned int*)(&sA[buf][w * 1024 + c * 512]),
          16, 0, 0);
#pragma unroll
    for (int c = 0; c < 2; ++c)
      __builtin_amdgcn_global_load_lds(
          (const __attribute__((address_space(1))) unsigned int*)(gB + (size_t)(srow + c * 16) * DM + k0 + skk),
          (__attribute__((address_space(3))) unsigned int*)(&sB[buf][w * 1024 + c * 512]),
          16, 0, 0);
  };

  stage(0, 0);
  int cur = 0;
  const int arow = wr * 64 + (lane & 15);
  const int brow = wc * 64 + (lane & 15);
  const int kf   = (((lane >> 4) ^ (((lane & 15) >> 1) & 3)) & 3) * 8;  // read-side XOR

  for (int t = 0; t < KSTEPS; ++t) {
    __syncthreads();
    if (t + 1 < KSTEPS) stage(cur ^ 1, t + 1);
    bf16x8 af[4], bfr[4];
#pragma unroll
    for (int i = 0; i < 4; ++i)
      af[i] = *(const bf16x8*)&sA[cur][(arow + i * 16) * BK + kf];
#pragma unroll
    for (int j = 0; j < 4; ++j)
      bfr[j] = *(const bf16x8*)&sB[cur][(brow + j * 16) * BK + kf];
#pragma unroll
    for (int i = 0; i < 4; ++i)
#pragma unroll
      for (int j = 0; j < 4; ++j)
        acc[i][j] = __builtin_amdgcn_mfma_f32_16x16x32_bf16(af[i], bfr[j], acc[i][j], 0, 0, 0);
    cur ^= 1;
  }

  if (n0 < 2048) {
    // K/Q block: row-major Z2; Q columns pre-scaled by scale*log2e (fp32)
    const float sc = (n0 >= 1024) ? SL2E_C : 1.0f;
#pragma unroll
    for (int i = 0; i < 4; ++i) {
#pragma unroll
      for (int j = 0; j < 4; ++j) {
        const int col = n0 + wc * 64 + j * 16 + (lane & 15);
        const float bb = bias[col];
#pragma unroll
        for (int r = 0; r < 4; ++r) {
          const int row = m0 + wr * 64 + i * 16 + (lane >> 4) * 4 + r;
          Z2[(size_t)row * E2 + col] = (bf16)((acc[i][j][r] + bb) * sc);
        }
      }
    }
  } else {
    // V block: transposed, sigma-permuted VT[n][h][d][k'] (b64 stores)
#pragma unroll
    for (int i = 0; i < 4; ++i) {
      const int rowb = m0 + wr * 64 + i * 16 + (lane >> 4) * 4;
      const int nb   = rowb >> 11;
      const int k    = rowb & 2047;
      const int ksig = (k & ~63) | (k & 32) | (((k >> 2) & 3) << 3) | (((k >> 4) & 1) << 2);
#pragma unroll
      for (int j = 0; j < 4; ++j) {
        const int col  = n0 + wc * 64 + j * 16 + (lane & 15);
        const float bb = bias[col];
        const int colv = col - 2048;
        const int h    = colv >> 6;
        const int d    = colv & 63;
        bf16x4 v4;
#pragma unroll
        for (int r = 0; r < 4; ++r) v4[r] = (bf16)(acc[i][j][r] + bb);
        *(bf16x4*)&VT[(((size_t)nb * NH + h) * HD + d) * SEQ + ksig] = v4;
      }
    }
  }
}

// ---------------- causal flash attention ----------------
// r27 champion body, unchanged: QB = KB = 64, 4 waves x 16 q-rows, 32 qtiles
// pair-scheduled (b, 31-b) -> 1024 UNIFORM blocks, 4/CU. XCD-local remap.
// Swapped QK^T, NO-MAX softmax (scale folded into Q; raw v_exp_f32),
// ones-MFMA denominator, all-DMA K/V staging, sigma-contiguous b128 reads.
#define QB 64
#define KB 64
#define NQT (SEQ / QB)   // 32

__global__ __launch_bounds__(256, 4) void attn_kernel(
    const bf16* __restrict__ Z2, const bf16* __restrict__ VT, float* __restrict__ out)
{
  __shared__ bf16 sK[2][KB][64];    // [buf][k][swizzled d]    16 KB
  __shared__ bf16 sVT[2][HD][64];   // [buf][d][sigma(k)^X(d)] 16 KB

  const int tid   = threadIdx.x;
  const int lane  = tid & 63;
  const int w     = tid >> 6;        // 0..3
  const int l15   = lane & 15;
  const int lhi   = lane >> 4;
  const int l7    = l15 & 7;
  const int e2    = l15 >> 3;        // 0/1

  const int flat  = blockIdx.x;
  const int xcd   = flat & 7;
  const int u     = flat >> 3;          // 0..127
  const int ctx   = xcd * 8 + (u & 7);
  const int pairb = u >> 3;             // 0..15
  const int h     = ctx & 15;
  const int n     = ctx >> 4;

  const size_t zb2 = (size_t)n * SEQ * E2;
  const size_t vtb = ((size_t)n * NH + h) * HD * SEQ;
  const int kcol0 = h * HD;
  const int qcol0 = DM + h * HD;

  const f32x4 z4 = {0.f, 0.f, 0.f, 0.f};
  const f32x4 neg4 = {-1e32f, -1e32f, -1e32f, -1e32f};

  const u32x4 onesu = {0x3F803F80u, 0x3F803F80u, 0x3F803F80u, 0x3F803F80u};
  const bf16x8 onesf = __builtin_bit_cast(bf16x8, onesu);

  const int krow_in = lane >> 3;                        // 0..7 within chunk
  const int kdblk   = ((lane & 7) ^ (lane >> 3)) * 8;   // swizzled d offset

  const size_t ob = (size_t)n * SEQ * DM;

  auto stageK = [&](int t, int buf) {
#pragma unroll
    for (int c = 0; c < 2; ++c) {
      const int cc = 2 * w + c;
      __builtin_amdgcn_global_load_lds(
          (const __attribute__((address_space(1))) unsigned int*)(
              Z2 + zb2 + (size_t)(t * KB + 8 * cc + krow_in) * E2 + kcol0 + kdblk),
          (__attribute__((address_space(3))) unsigned int*)(&sK[buf][8 * cc][0]),
          16, 0, 0);
    }
  };
  auto stageV = [&](int t, int buf) {
#pragma unroll
    for (int c = 0; c < 2; ++c) {
      const int cc   = 2 * w + c;
      const int dsrc = 8 * cc + (lane >> 3);
      const int blk  = (lane & 7) ^ ((dsrc ^ (dsrc >> 3)) & 7);
      __builtin_amdgcn_global_load_lds(
          (const __attribute__((address_space(1))) unsigned int*)(
              VT + vtb + (size_t)dsrc * SEQ + t * KB + blk * 8),
          (__attribute__((address_space(3))) unsigned int*)(&sVT[buf][8 * cc][0]),
          16, 0, 0);
    }
  };

#pragma unroll 1
  for (int phase = 0; phase < 2; ++phase) {
    const int qtile = phase == 0 ? pairb : (NQT - 1 - pairb);
    const int qwave = qtile * QB + w * 16;   // wave's 16 q-rows
    const int T     = qtile + 1;             // KV 64-tiles this phase

    bf16x8 qf[2];
    {
      const int qrow = qwave + l15;
#pragma unroll
      for (int kk = 0; kk < 2; ++kk)
        qf[kk] = *(const bf16x8*)&Z2[zb2 + (size_t)qrow * E2 + qcol0 + kk * 32 + lhi * 8];
    }

    f32x4 accO[4];
    f32x4 accL;
#pragma unroll
    for (int dt = 0; dt < 4; ++dt) accO[dt] = z4;
    accL = z4;

    stageK(0, 0);
    stageV(0, 0);
    __syncthreads();

#pragma unroll 1
    for (int t = 0; t < T; ++t) {
      const int cur = t & 1;
      if (t + 1 < T) { stageK(t + 1, cur ^ 1); stageV(t + 1, cur ^ 1); }

      f32x4 st[4];
      __builtin_amdgcn_s_setprio(1);
#pragma unroll
      for (int kt = 0; kt < 4; ++kt) {
        const int blk0 = (lhi ^ l7) * 8;
        const int blk1 = ((4 + lhi) ^ l7) * 8;
        bf16x8 kf0 = *(const bf16x8*)&sK[cur][kt * 16 + l15][blk0];
        st[kt] = __builtin_amdgcn_mfma_f32_16x16x32_bf16(kf0, qf[0], z4, 0, 0, 0);
        bf16x8 kf1 = *(const bf16x8*)&sK[cur][kt * 16 + l15][blk1];
        st[kt] = __builtin_amdgcn_mfma_f32_16x16x32_bf16(kf1, qf[1], st[kt], 0, 0, 0);
      }
      __builtin_amdgcn_s_setprio(0);

      if (t == T - 1) {
#pragma unroll
        for (int kt = 0; kt < 4; ++kt) {
          if (kt > w) st[kt] = neg4;
          else if (kt == w) {
#pragma unroll
            for (int r = 0; r < 4; ++r)
              if (lhi * 4 + r > l15) st[kt][r] = -1e32f;
          }
        }
      }

      // NO-MAX softmax, raw v_exp_f32 (args bounded; masked -> exactly 0)
      bf16x8 pb[2];
#pragma unroll
      for (int c = 0; c < 2; ++c) {
        u32x4 pu;
#pragma unroll
        for (int i = 0; i < 4; ++i) {
          const int kt = 2 * c + (i >> 1);
          const int r  = (2 * i) & 3;
          const float p0 = __builtin_amdgcn_exp2f(st[kt][r]);
          const float p1 = __builtin_amdgcn_exp2f(st[kt][r + 1]);
          const bf16 b0v = (bf16)p0;
          const bf16 b1v = (bf16)p1;
          pu[i] = (unsigned int)__builtin_bit_cast(unsigned short, b0v)
                | ((unsigned int)__builtin_bit_cast(unsigned short, b1v) << 16);
        }
        pb[c] = __builtin_bit_cast(bf16x8, pu);
      }

      __builtin_amdgcn_s_setprio(1);
#pragma unroll
      for (int c = 0; c < 2; ++c)
        accL = __builtin_amdgcn_mfma_f32_16x16x32_bf16(onesf, pb[c], accL, 0, 0, 0);

#pragma unroll
      for (int c = 0; c < 2; ++c) {
#pragma unroll
        for (int dt = 0; dt < 4; ++dt) {
          const int idxv = ((4 * c + lhi) ^ (l7 ^ ((2 * dt + e2) & 7))) << 3;
          const bf16x8 av = *(const bf16x8*)&sVT[cur][dt * 16 + l15][idxv];
          accO[dt] = __builtin_amdgcn_mfma_f32_16x16x32_bf16(av, pb[c], accO[dt], 0, 0, 0);
        }
      }
      __builtin_amdgcn_s_setprio(0);

      __syncthreads();
    }

    {
      const float inv  = 1.f / accL[0];
      const int   qrow = qwave + l15;
#pragma unroll
      for (int dt = 0; dt < 4; ++dt) {
        float4 o;
        o.x = accO[dt][0] * inv;
        o.y = accO[dt][1] * inv;
        o.z = accO[dt][2] * inv;
        o.w = accO[dt][3] * inv;
        *(float4*)&out[ob + (size_t)qrow * DM + h * HD + dt * 16 + lhi * 4] = o;
      }
    }
  }
}

extern "C" void kernel_launch(void* const* d_in, const int* in_sizes, int n_in,
                              void* d_out, int out_size, void* d_ws, size_t ws_size,
                              hipStream_t stream) {
  const float* x    = (const float*)d_in[0];
  const float* W    = (const float*)d_in[1];
  const float* bias = (const float*)d_in[2];
  float* out = (float*)d_out;

  // workspace: xb 16MB | Wb 6MB | Z2 32MB | VT 16MB  (= 70MB)
  bf16* xb = (bf16*)d_ws;
  bf16* Wb = xb + (size_t)NBAT * SEQ * DM;
  bf16* Z2 = Wb + (size_t)E3 * DM;
  bf16* VT = Z2 + (size_t)NBAT * SEQ * E2;

  cvt2_bf16_kernel<<<1536, 256, 0, stream>>>(x, xb, NBAT * SEQ * DM / 8,
                                             W, Wb, E3 * DM / 8);

  dim3 g1(NBAT * SEQ / BM, E3 / BN);
  qkv_gemm_kernel<<<g1, 256, 0, stream>>>(xb, Wb, bias, Z2, VT);

  attn_kernel<<<1024, 256, 0, stream>>>(Z2, VT, out);   // uniform, 4/CU
}

// Round 29
// 132.372 us; speedup vs baseline: 1.1893x; 1.0004x over previous
//
#include <hip/hip_runtime.h>
#include <hip/hip_bf16.h>

typedef __bf16 bf16;
typedef __bf16 bf16x4 __attribute__((ext_vector_type(4)));
typedef __bf16 bf16x8 __attribute__((ext_vector_type(8)));
typedef float f32x4 __attribute__((ext_vector_type(4)));
typedef unsigned int u32x4 __attribute__((ext_vector_type(4)));

#define SEQ   2048
#define NBAT  4
#define DM    1024
#define NH    16
#define HD    64
#define E3    3072
#define E2    2048   // Z2 row stride: [K(0:1024) | Q_scaled(1024:2048)]

#define SL2E_C 0.04508422f   // (1/32) * log2(e)

// ---------------- fp32 -> bf16 convert (x and W fused in one launch) ----------------
__global__ void cvt2_bf16_kernel(const float* __restrict__ a, bf16* __restrict__ oa, int na8,
                                 const float* __restrict__ b, bf16* __restrict__ ob, int nb8) {
  const int stride = gridDim.x * blockDim.x;
  const int ntot = na8 + nb8;
  for (int i = blockIdx.x * blockDim.x + threadIdx.x; i < ntot; i += stride) {
    const float* src;
    bf16* dst;
    int j;
    if (i < na8) { src = a; dst = oa; j = i; }
    else         { src = b; dst = ob; j = i - na8; }
    const float4* p = (const float4*)(src + (size_t)j * 8);
    float4 x = p[0];
    float4 y = p[1];
    bf16x8 o;
    o[0] = (bf16)x.x; o[1] = (bf16)x.y; o[2] = (bf16)x.z; o[3] = (bf16)x.w;
    o[4] = (bf16)y.x; o[5] = (bf16)y.y; o[6] = (bf16)y.z; o[7] = (bf16)y.w;
    *(bf16x8*)(dst + (size_t)j * 8) = o;
  }
}

// ---------------- QKV projection GEMM ----------------
// 2D grid; LDS XOR-block swizzle on sA/sB (conflict-free, r26).
// r29: launch bounds back to (256,2) — (256,3) regressed per-dispatch time.
// K cols -> Z2 row-major; Q cols pre-scaled by scale*log2e; V cols ->
// sigma-permuted transposed VT (b64 stores).
#define BM 128
#define BN 128
#define BK 32
#define KSTEPS (DM / BK)

__global__ __launch_bounds__(256, 2) void qkv_gemm_kernel(
    const bf16* __restrict__ A, const bf16* __restrict__ B,
    const float* __restrict__ bias, bf16* __restrict__ Z2, bf16* __restrict__ VT)
{
  __shared__ bf16 sA[2][BM * BK];
  __shared__ bf16 sB[2][BN * BK];

  const int tid  = threadIdx.x;
  const int lane = tid & 63;
  const int w    = tid >> 6;
  const int wr   = w >> 1;
  const int wc   = w & 1;
  const int m0   = blockIdx.x * BM;
  const int n0   = blockIdx.y * BN;

  const f32x4 z4 = {0.f, 0.f, 0.f, 0.f};
  f32x4 acc[4][4];
#pragma unroll
  for (int i = 0; i < 4; ++i)
#pragma unroll
    for (int j = 0; j < 4; ++j)
      acc[i][j] = z4;

  const int srow = w * 32 + (lane >> 2);
  const int skk  = ((lane & 3) ^ ((lane >> 3) & 3)) * 8;   // source pre-swizzle
  const bf16* gA = A + (size_t)m0 * DM;
  const bf16* gB = B + (size_t)n0 * DM;

  auto stage = [&](int buf, int t) {
    const int k0 = t * BK;
#pragma unroll
    for (int c = 0; c < 2; ++c)
      __builtin_amdgcn_global_load_lds(
          (const __attribute__((address_space(1))) unsigned int*)(gA + (size_t)(srow + c * 16) * DM + k0 + skk),
          (__attribute__((address_space(3))) unsigned int*)(&sA[buf][w * 1024 + c * 512]),
          16, 0, 0);
#pragma unroll
    for (int c = 0; c < 2; ++c)
      __builtin_amdgcn_global_load_lds(
          (const __attribute__((address_space(1))) unsigned int*)(gB + (size_t)(srow + c * 16) * DM + k0 + skk),
          (__attribute__((address_space(3))) unsigned int*)(&sB[buf][w * 1024 + c * 512]),
          16, 0, 0);
  };

  stage(0, 0);
  int cur = 0;
  const int arow = wr * 64 + (lane & 15);
  const int brow = wc * 64 + (lane & 15);
  const int kf   = (((lane >> 4) ^ (((lane & 15) >> 1) & 3)) & 3) * 8;  // read-side XOR

  for (int t = 0; t < KSTEPS; ++t) {
    __syncthreads();
    if (t + 1 < KSTEPS) stage(cur ^ 1, t + 1);
    bf16x8 af[4], bfr[4];
#pragma unroll
    for (int i = 0; i < 4; ++i)
      af[i] = *(const bf16x8*)&sA[cur][(arow + i * 16) * BK + kf];
#pragma unroll
    for (int j = 0; j < 4; ++j)
      bfr[j] = *(const bf16x8*)&sB[cur][(brow + j * 16) * BK + kf];
#pragma unroll
    for (int i = 0; i < 4; ++i)
#pragma unroll
      for (int j = 0; j < 4; ++j)
        acc[i][j] = __builtin_amdgcn_mfma_f32_16x16x32_bf16(af[i], bfr[j], acc[i][j], 0, 0, 0);
    cur ^= 1;
  }

  if (n0 < 2048) {
    // K/Q block: row-major Z2; Q columns pre-scaled by scale*log2e (fp32)
    const float sc = (n0 >= 1024) ? SL2E_C : 1.0f;
#pragma unroll
    for (int i = 0; i < 4; ++i) {
#pragma unroll
      for (int j = 0; j < 4; ++j) {
        const int col = n0 + wc * 64 + j * 16 + (lane & 15);
        const float bb = bias[col];
#pragma unroll
        for (int r = 0; r < 4; ++r) {
          const int row = m0 + wr * 64 + i * 16 + (lane >> 4) * 4 + r;
          Z2[(size_t)row * E2 + col] = (bf16)((acc[i][j][r] + bb) * sc);
        }
      }
    }
  } else {
    // V block: transposed, sigma-permuted VT[n][h][d][k'] (b64 stores)
#pragma unroll
    for (int i = 0; i < 4; ++i) {
      const int rowb = m0 + wr * 64 + i * 16 + (lane >> 4) * 4;
      const int nb   = rowb >> 11;
      const int k    = rowb & 2047;
      const int ksig = (k & ~63) | (k & 32) | (((k >> 2) & 3) << 3) | (((k >> 4) & 1) << 2);
#pragma unroll
      for (int j = 0; j < 4; ++j) {
        const int col  = n0 + wc * 64 + j * 16 + (lane & 15);
        const float bb = bias[col];
        const int colv = col - 2048;
        const int h    = colv >> 6;
        const int d    = colv & 63;
        bf16x4 v4;
#pragma unroll
        for (int r = 0; r < 4; ++r) v4[r] = (bf16)(acc[i][j][r] + bb);
        *(bf16x4*)&VT[(((size_t)nb * NH + h) * HD + d) * SEQ + ksig] = v4;
      }
    }
  }
}

// ---------------- causal flash attention ----------------
// r27 champion body with setprio REMOVED (m190: setprio is null-to-negative
// on barrier-synced lockstep kernels; this is one — 4 waves, 1 barrier/tile).
// QB = KB = 64, 4 waves x 16 q-rows, 32 qtiles pair-scheduled (b, 31-b) ->
// 1024 UNIFORM blocks, 4/CU. XCD-local remap. Swapped QK^T, NO-MAX softmax
// (scale folded into Q; raw v_exp_f32), ones-MFMA denominator, all-DMA K/V
// staging, sigma-contiguous b128 sVT reads.
#define QB 64
#define KB 64
#define NQT (SEQ / QB)   // 32

__global__ __launch_bounds__(256, 4) void attn_kernel(
    const bf16* __restrict__ Z2, const bf16* __restrict__ VT, float* __restrict__ out)
{
  __shared__ bf16 sK[2][KB][64];    // [buf][k][swizzled d]    16 KB
  __shared__ bf16 sVT[2][HD][64];   // [buf][d][sigma(k)^X(d)] 16 KB

  const int tid   = threadIdx.x;
  const int lane  = tid & 63;
  const int w     = tid >> 6;        // 0..3
  const int l15   = lane & 15;
  const int lhi   = lane >> 4;
  const int l7    = l15 & 7;
  const int e2    = l15 >> 3;        // 0/1

  const int flat  = blockIdx.x;
  const int xcd   = flat & 7;
  const int u     = flat >> 3;          // 0..127
  const int ctx   = xcd * 8 + (u & 7);
  const int pairb = u >> 3;             // 0..15
  const int h     = ctx & 15;
  const int n     = ctx >> 4;

  const size_t zb2 = (size_t)n * SEQ * E2;
  const size_t vtb = ((size_t)n * NH + h) * HD * SEQ;
  const int kcol0 = h * HD;
  const int qcol0 = DM + h * HD;

  const f32x4 z4 = {0.f, 0.f, 0.f, 0.f};
  const f32x4 neg4 = {-1e32f, -1e32f, -1e32f, -1e32f};

  const u32x4 onesu = {0x3F803F80u, 0x3F803F80u, 0x3F803F80u, 0x3F803F80u};
  const bf16x8 onesf = __builtin_bit_cast(bf16x8, onesu);

  const int krow_in = lane >> 3;                        // 0..7 within chunk
  const int kdblk   = ((lane & 7) ^ (lane >> 3)) * 8;   // swizzled d offset

  const size_t ob = (size_t)n * SEQ * DM;

  auto stageK = [&](int t, int buf) {
#pragma unroll
    for (int c = 0; c < 2; ++c) {
      const int cc = 2 * w + c;
      __builtin_amdgcn_global_load_lds(
          (const __attribute__((address_space(1))) unsigned int*)(
              Z2 + zb2 + (size_t)(t * KB + 8 * cc + krow_in) * E2 + kcol0 + kdblk),
          (__attribute__((address_space(3))) unsigned int*)(&sK[buf][8 * cc][0]),
          16, 0, 0);
    }
  };
  auto stageV = [&](int t, int buf) {
#pragma unroll
    for (int c = 0; c < 2; ++c) {
      const int cc   = 2 * w + c;
      const int dsrc = 8 * cc + (lane >> 3);
      const int blk  = (lane & 7) ^ ((dsrc ^ (dsrc >> 3)) & 7);
      __builtin_amdgcn_global_load_lds(
          (const __attribute__((address_space(1))) unsigned int*)(
              VT + vtb + (size_t)dsrc * SEQ + t * KB + blk * 8),
          (__attribute__((address_space(3))) unsigned int*)(&sVT[buf][8 * cc][0]),
          16, 0, 0);
    }
  };

#pragma unroll 1
  for (int phase = 0; phase < 2; ++phase) {
    const int qtile = phase == 0 ? pairb : (NQT - 1 - pairb);
    const int qwave = qtile * QB + w * 16;   // wave's 16 q-rows
    const int T     = qtile + 1;             // KV 64-tiles this phase

    bf16x8 qf[2];
    {
      const int qrow = qwave + l15;
#pragma unroll
      for (int kk = 0; kk < 2; ++kk)
        qf[kk] = *(const bf16x8*)&Z2[zb2 + (size_t)qrow * E2 + qcol0 + kk * 32 + lhi * 8];
    }

    f32x4 accO[4];
    f32x4 accL;
#pragma unroll
    for (int dt = 0; dt < 4; ++dt) accO[dt] = z4;
    accL = z4;

    stageK(0, 0);
    stageV(0, 0);
    __syncthreads();

#pragma unroll 1
    for (int t = 0; t < T; ++t) {
      const int cur = t & 1;
      if (t + 1 < T) { stageK(t + 1, cur ^ 1); stageV(t + 1, cur ^ 1); }

      f32x4 st[4];
#pragma unroll
      for (int kt = 0; kt < 4; ++kt) {
        const int blk0 = (lhi ^ l7) * 8;
        const int blk1 = ((4 + lhi) ^ l7) * 8;
        bf16x8 kf0 = *(const bf16x8*)&sK[cur][kt * 16 + l15][blk0];
        st[kt] = __builtin_amdgcn_mfma_f32_16x16x32_bf16(kf0, qf[0], z4, 0, 0, 0);
        bf16x8 kf1 = *(const bf16x8*)&sK[cur][kt * 16 + l15][blk1];
        st[kt] = __builtin_amdgcn_mfma_f32_16x16x32_bf16(kf1, qf[1], st[kt], 0, 0, 0);
      }

      if (t == T - 1) {
#pragma unroll
        for (int kt = 0; kt < 4; ++kt) {
          if (kt > w) st[kt] = neg4;
          else if (kt == w) {
#pragma unroll
            for (int r = 0; r < 4; ++r)
              if (lhi * 4 + r > l15) st[kt][r] = -1e32f;
          }
        }
      }

      // NO-MAX softmax, raw v_exp_f32 (args bounded; masked -> exactly 0)
      bf16x8 pb[2];
#pragma unroll
      for (int c = 0; c < 2; ++c) {
        u32x4 pu;
#pragma unroll
        for (int i = 0; i < 4; ++i) {
          const int kt = 2 * c + (i >> 1);
          const int r  = (2 * i) & 3;
          const float p0 = __builtin_amdgcn_exp2f(st[kt][r]);
          const float p1 = __builtin_amdgcn_exp2f(st[kt][r + 1]);
          const bf16 b0v = (bf16)p0;
          const bf16 b1v = (bf16)p1;
          pu[i] = (unsigned int)__builtin_bit_cast(unsigned short, b0v)
                | ((unsigned int)__builtin_bit_cast(unsigned short, b1v) << 16);
        }
        pb[c] = __builtin_bit_cast(bf16x8, pu);
      }

      // denominator via ones-MFMA
#pragma unroll
      for (int c = 0; c < 2; ++c)
        accL = __builtin_amdgcn_mfma_f32_16x16x32_bf16(onesf, pb[c], accL, 0, 0, 0);

      // O^T += V^T·P^T : av = single b128 (sigma-contiguous, XOR-swizzled)
#pragma unroll
      for (int c = 0; c < 2; ++c) {
#pragma unroll
        for (int dt = 0; dt < 4; ++dt) {
          const int idxv = ((4 * c + lhi) ^ (l7 ^ ((2 * dt + e2) & 7))) << 3;
          const bf16x8 av = *(const bf16x8*)&sVT[cur][dt * 16 + l15][idxv];
          accO[dt] = __builtin_amdgcn_mfma_f32_16x16x32_bf16(av, pb[c], accO[dt], 0, 0, 0);
        }
      }

      __syncthreads();   // the ONLY barrier per tile (drains DMA + orders bufs)
    }

    {
      const float inv  = 1.f / accL[0];
      const int   qrow = qwave + l15;
#pragma unroll
      for (int dt = 0; dt < 4; ++dt) {
        float4 o;
        o.x = accO[dt][0] * inv;
        o.y = accO[dt][1] * inv;
        o.z = accO[dt][2] * inv;
        o.w = accO[dt][3] * inv;
        *(float4*)&out[ob + (size_t)qrow * DM + h * HD + dt * 16 + lhi * 4] = o;
      }
    }
  }
}

extern "C" void kernel_launch(void* const* d_in, const int* in_sizes, int n_in,
                              void* d_out, int out_size, void* d_ws, size_t ws_size,
                              hipStream_t stream) {
  const float* x    = (const float*)d_in[0];
  const float* W    = (const float*)d_in[1];
  const float* bias = (const float*)d_in[2];
  float* out = (float*)d_out;

  // workspace: xb 16MB | Wb 6MB | Z2 32MB | VT 16MB  (= 70MB)
  bf16* xb = (bf16*)d_ws;
  bf16* Wb = xb + (size_t)NBAT * SEQ * DM;
  bf16* Z2 = Wb + (size_t)E3 * DM;
  bf16* VT = Z2 + (size_t)NBAT * SEQ * E2;

  cvt2_bf16_kernel<<<1536, 256, 0, stream>>>(x, xb, NBAT * SEQ * DM / 8,
                                             W, Wb, E3 * DM / 8);

  dim3 g1(NBAT * SEQ / BM, E3 / BN);
  qkv_gemm_kernel<<<g1, 256, 0, stream>>>(xb, Wb, bias, Z2, VT);

  attn_kernel<<<1024, 256, 0, stream>>>(Z2, VT, out);   // uniform, 4/CU
}

// Round 30
// 129.337 us; speedup vs baseline: 1.2172x; 1.0235x over previous
//
#include <hip/hip_runtime.h>
#include <hip/hip_bf16.h>

typedef __bf16 bf16;
typedef __bf16 bf16x4 __attribute__((ext_vector_type(4)));
typedef __bf16 bf16x8 __attribute__((ext_vector_type(8)));
typedef float f32x4 __attribute__((ext_vector_type(4)));
typedef unsigned int u32x4 __attribute__((ext_vector_type(4)));

#define SEQ   2048
#define NBAT  4
#define DM    1024
#define NH    16
#define HD    64
#define E3    3072
#define E2    2048   // Z2 row stride: [K(0:1024) | Q_scaled(1024:2048)]

#define SL2E_C 0.04508422f   // (1/32) * log2(e)

// ---------------- fp32 -> bf16 convert (x and W fused in one launch) ----------------
__global__ void cvt2_bf16_kernel(const float* __restrict__ a, bf16* __restrict__ oa, int na8,
                                 const float* __restrict__ b, bf16* __restrict__ ob, int nb8) {
  const int stride = gridDim.x * blockDim.x;
  const int ntot = na8 + nb8;
  for (int i = blockIdx.x * blockDim.x + threadIdx.x; i < ntot; i += stride) {
    const float* src;
    bf16* dst;
    int j;
    if (i < na8) { src = a; dst = oa; j = i; }
    else         { src = b; dst = ob; j = i - na8; }
    const float4* p = (const float4*)(src + (size_t)j * 8);
    float4 x = p[0];
    float4 y = p[1];
    bf16x8 o;
    o[0] = (bf16)x.x; o[1] = (bf16)x.y; o[2] = (bf16)x.z; o[3] = (bf16)x.w;
    o[4] = (bf16)y.x; o[5] = (bf16)y.y; o[6] = (bf16)y.z; o[7] = (bf16)y.w;
    *(bf16x8*)(dst + (size_t)j * 8) = o;
  }
}

// ---------------- QKV projection GEMM ----------------
// 2D grid; LDS XOR-block swizzle on sA/sB (conflict-free, r26).
// r30: 3-buffer deep pipeline with COUNTED vmcnt (T4). stage(t+2) issued at
// iter t; end-of-iter barrier = s_waitcnt vmcnt(4) lgkmcnt(0) + s_barrier:
// drains stage(t+1) (issued a full iteration earlier — 2 compute phases of
// latency cover) while stage(t+2)'s 4 loads stay in flight across the
// barrier. Tail: vmcnt(0) when no new stage was issued (else vmcnt(4)
// would pass without draining).
// K cols -> Z2 row-major; Q cols pre-scaled by scale*log2e; V cols ->
// sigma-permuted transposed VT (b64 stores).
#define BM 128
#define BN 128
#define BK 32
#define KSTEPS (DM / BK)

__global__ __launch_bounds__(256, 2) void qkv_gemm_kernel(
    const bf16* __restrict__ A, const bf16* __restrict__ B,
    const float* __restrict__ bias, bf16* __restrict__ Z2, bf16* __restrict__ VT)
{
  __shared__ bf16 sA[3][BM * BK];   // 24 KB
  __shared__ bf16 sB[3][BN * BK];   // 24 KB

  const int tid  = threadIdx.x;
  const int lane = tid & 63;
  const int w    = tid >> 6;
  const int wr   = w >> 1;
  const int wc   = w & 1;
  const int m0   = blockIdx.x * BM;
  const int n0   = blockIdx.y * BN;

  const f32x4 z4 = {0.f, 0.f, 0.f, 0.f};
  f32x4 acc[4][4];
#pragma unroll
  for (int i = 0; i < 4; ++i)
#pragma unroll
    for (int j = 0; j < 4; ++j)
      acc[i][j] = z4;

  const int srow = w * 32 + (lane >> 2);
  const int skk  = ((lane & 3) ^ ((lane >> 3) & 3)) * 8;   // source pre-swizzle
  const bf16* gA = A + (size_t)m0 * DM;
  const bf16* gB = B + (size_t)n0 * DM;

  auto stage = [&](int t, int buf) {
    const int k0 = t * BK;
#pragma unroll
    for (int c = 0; c < 2; ++c)
      __builtin_amdgcn_global_load_lds(
          (const __attribute__((address_space(1))) unsigned int*)(gA + (size_t)(srow + c * 16) * DM + k0 + skk),
          (__attribute__((address_space(3))) unsigned int*)(&sA[buf][w * 1024 + c * 512]),
          16, 0, 0);
#pragma unroll
    for (int c = 0; c < 2; ++c)
      __builtin_amdgcn_global_load_lds(
          (const __attribute__((address_space(1))) unsigned int*)(gB + (size_t)(srow + c * 16) * DM + k0 + skk),
          (__attribute__((address_space(3))) unsigned int*)(&sB[buf][w * 1024 + c * 512]),
          16, 0, 0);
  };

  // prologue: tiles 0,1 staged; drain tile 0 only (tile 1 stays in flight)
  stage(0, 0);
  stage(1, 1);
  asm volatile("s_waitcnt vmcnt(4)" ::: "memory");
  __builtin_amdgcn_s_barrier();
  asm volatile("" ::: "memory");

  const int arow = wr * 64 + (lane & 15);
  const int brow = wc * 64 + (lane & 15);
  const int kf   = (((lane >> 4) ^ (((lane & 15) >> 1) & 3)) & 3) * 8;  // read-side XOR

  int cur = 0;   // compute buffer (tile t)
  int nxt = 2;   // staging buffer (tile t+2)
#pragma unroll 1
  for (int t = 0; t < KSTEPS; ++t) {
    if (t + 2 < KSTEPS) stage(t + 2, nxt);

    bf16x8 af[4], bfr[4];
#pragma unroll
    for (int i = 0; i < 4; ++i)
      af[i] = *(const bf16x8*)&sA[cur][(arow + i * 16) * BK + kf];
#pragma unroll
    for (int j = 0; j < 4; ++j)
      bfr[j] = *(const bf16x8*)&sB[cur][(brow + j * 16) * BK + kf];
#pragma unroll
    for (int i = 0; i < 4; ++i)
#pragma unroll
      for (int j = 0; j < 4; ++j)
        acc[i][j] = __builtin_amdgcn_mfma_f32_16x16x32_bf16(af[i], bfr[j], acc[i][j], 0, 0, 0);

    if (t + 1 < KSTEPS) {
      if (t + 2 < KSTEPS)
        asm volatile("s_waitcnt vmcnt(4) lgkmcnt(0)" ::: "memory");  // drain stage(t+1) only
      else
        asm volatile("s_waitcnt vmcnt(0) lgkmcnt(0)" ::: "memory");  // tail: full drain
      __builtin_amdgcn_s_barrier();
      asm volatile("" ::: "memory");
    }
    cur = (cur == 2) ? 0 : cur + 1;
    nxt = (nxt == 2) ? 0 : nxt + 1;
  }

  if (n0 < 2048) {
    // K/Q block: row-major Z2; Q columns pre-scaled by scale*log2e (fp32)
    const float sc = (n0 >= 1024) ? SL2E_C : 1.0f;
#pragma unroll
    for (int i = 0; i < 4; ++i) {
#pragma unroll
      for (int j = 0; j < 4; ++j) {
        const int col = n0 + wc * 64 + j * 16 + (lane & 15);
        const float bb = bias[col];
#pragma unroll
        for (int r = 0; r < 4; ++r) {
          const int row = m0 + wr * 64 + i * 16 + (lane >> 4) * 4 + r;
          Z2[(size_t)row * E2 + col] = (bf16)((acc[i][j][r] + bb) * sc);
        }
      }
    }
  } else {
    // V block: transposed, sigma-permuted VT[n][h][d][k'] (b64 stores)
#pragma unroll
    for (int i = 0; i < 4; ++i) {
      const int rowb = m0 + wr * 64 + i * 16 + (lane >> 4) * 4;
      const int nb   = rowb >> 11;
      const int k    = rowb & 2047;
      const int ksig = (k & ~63) | (k & 32) | (((k >> 2) & 3) << 3) | (((k >> 4) & 1) << 2);
#pragma unroll
      for (int j = 0; j < 4; ++j) {
        const int col  = n0 + wc * 64 + j * 16 + (lane & 15);
        const float bb = bias[col];
        const int colv = col - 2048;
        const int h    = colv >> 6;
        const int d    = colv & 63;
        bf16x4 v4;
#pragma unroll
        for (int r = 0; r < 4; ++r) v4[r] = (bf16)(acc[i][j][r] + bb);
        *(bf16x4*)&VT[(((size_t)nb * NH + h) * HD + d) * SEQ + ksig] = v4;
      }
    }
  }
}

// ---------------- causal flash attention ----------------
// r29 champion body, unchanged: QB = KB = 64, 4 waves x 16 q-rows, 32 qtiles
// pair-scheduled (b, 31-b) -> 1024 UNIFORM blocks, 4/CU. XCD-local remap.
// Swapped QK^T, NO-MAX softmax (scale folded into Q; raw v_exp_f32),
// ones-MFMA denominator, all-DMA K/V staging, sigma-contiguous b128 reads.
#define QB 64
#define KB 64
#define NQT (SEQ / QB)   // 32

__global__ __launch_bounds__(256, 4) void attn_kernel(
    const bf16* __restrict__ Z2, const bf16* __restrict__ VT, float* __restrict__ out)
{
  __shared__ bf16 sK[2][KB][64];    // [buf][k][swizzled d]    16 KB
  __shared__ bf16 sVT[2][HD][64];   // [buf][d][sigma(k)^X(d)] 16 KB

  const int tid   = threadIdx.x;
  const int lane  = tid & 63;
  const int w     = tid >> 6;        // 0..3
  const int l15   = lane & 15;
  const int lhi   = lane >> 4;
  const int l7    = l15 & 7;
  const int e2    = l15 >> 3;        // 0/1

  const int flat  = blockIdx.x;
  const int xcd   = flat & 7;
  const int u     = flat >> 3;          // 0..127
  const int ctx   = xcd * 8 + (u & 7);
  const int pairb = u >> 3;             // 0..15
  const int h     = ctx & 15;
  const int n     = ctx >> 4;

  const size_t zb2 = (size_t)n * SEQ * E2;
  const size_t vtb = ((size_t)n * NH + h) * HD * SEQ;
  const int kcol0 = h * HD;
  const int qcol0 = DM + h * HD;

  const f32x4 z4 = {0.f, 0.f, 0.f, 0.f};
  const f32x4 neg4 = {-1e32f, -1e32f, -1e32f, -1e32f};

  const u32x4 onesu = {0x3F803F80u, 0x3F803F80u, 0x3F803F80u, 0x3F803F80u};
  const bf16x8 onesf = __builtin_bit_cast(bf16x8, onesu);

  const int krow_in = lane >> 3;                        // 0..7 within chunk
  const int kdblk   = ((lane & 7) ^ (lane >> 3)) * 8;   // swizzled d offset

  const size_t ob = (size_t)n * SEQ * DM;

  auto stageK = [&](int t, int buf) {
#pragma unroll
    for (int c = 0; c < 2; ++c) {
      const int cc = 2 * w + c;
      __builtin_amdgcn_global_load_lds(
          (const __attribute__((address_space(1))) unsigned int*)(
              Z2 + zb2 + (size_t)(t * KB + 8 * cc + krow_in) * E2 + kcol0 + kdblk),
          (__attribute__((address_space(3))) unsigned int*)(&sK[buf][8 * cc][0]),
          16, 0, 0);
    }
  };
  auto stageV = [&](int t, int buf) {
#pragma unroll
    for (int c = 0; c < 2; ++c) {
      const int cc   = 2 * w + c;
      const int dsrc = 8 * cc + (lane >> 3);
      const int blk  = (lane & 7) ^ ((dsrc ^ (dsrc >> 3)) & 7);
      __builtin_amdgcn_global_load_lds(
          (const __attribute__((address_space(1))) unsigned int*)(
              VT + vtb + (size_t)dsrc * SEQ + t * KB + blk * 8),
          (__attribute__((address_space(3))) unsigned int*)(&sVT[buf][8 * cc][0]),
          16, 0, 0);
    }
  };

#pragma unroll 1
  for (int phase = 0; phase < 2; ++phase) {
    const int qtile = phase == 0 ? pairb : (NQT - 1 - pairb);
    const int qwave = qtile * QB + w * 16;   // wave's 16 q-rows
    const int T     = qtile + 1;             // KV 64-tiles this phase

    bf16x8 qf[2];
    {
      const int qrow = qwave + l15;
#pragma unroll
      for (int kk = 0; kk < 2; ++kk)
        qf[kk] = *(const bf16x8*)&Z2[zb2 + (size_t)qrow * E2 + qcol0 + kk * 32 + lhi * 8];
    }

    f32x4 accO[4];
    f32x4 accL;
#pragma unroll
    for (int dt = 0; dt < 4; ++dt) accO[dt] = z4;
    accL = z4;

    stageK(0, 0);
    stageV(0, 0);
    __syncthreads();

#pragma unroll 1
    for (int t = 0; t < T; ++t) {
      const int cur = t & 1;
      if (t + 1 < T) { stageK(t + 1, cur ^ 1); stageV(t + 1, cur ^ 1); }

      f32x4 st[4];
#pragma unroll
      for (int kt = 0; kt < 4; ++kt) {
        const int blk0 = (lhi ^ l7) * 8;
        const int blk1 = ((4 + lhi) ^ l7) * 8;
        bf16x8 kf0 = *(const bf16x8*)&sK[cur][kt * 16 + l15][blk0];
        st[kt] = __builtin_amdgcn_mfma_f32_16x16x32_bf16(kf0, qf[0], z4, 0, 0, 0);
        bf16x8 kf1 = *(const bf16x8*)&sK[cur][kt * 16 + l15][blk1];
        st[kt] = __builtin_amdgcn_mfma_f32_16x16x32_bf16(kf1, qf[1], st[kt], 0, 0, 0);
      }

      if (t == T - 1) {
#pragma unroll
        for (int kt = 0; kt < 4; ++kt) {
          if (kt > w) st[kt] = neg4;
          else if (kt == w) {
#pragma unroll
            for (int r = 0; r < 4; ++r)
              if (lhi * 4 + r > l15) st[kt][r] = -1e32f;
          }
        }
      }

      // NO-MAX softmax, raw v_exp_f32 (args bounded; masked -> exactly 0)
      bf16x8 pb[2];
#pragma unroll
      for (int c = 0; c < 2; ++c) {
        u32x4 pu;
#pragma unroll
        for (int i = 0; i < 4; ++i) {
          const int kt = 2 * c + (i >> 1);
          const int r  = (2 * i) & 3;
          const float p0 = __builtin_amdgcn_exp2f(st[kt][r]);
          const float p1 = __builtin_amdgcn_exp2f(st[kt][r + 1]);
          const bf16 b0v = (bf16)p0;
          const bf16 b1v = (bf16)p1;
          pu[i] = (unsigned int)__builtin_bit_cast(unsigned short, b0v)
                | ((unsigned int)__builtin_bit_cast(unsigned short, b1v) << 16);
        }
        pb[c] = __builtin_bit_cast(bf16x8, pu);
      }

      // denominator via ones-MFMA
#pragma unroll
      for (int c = 0; c < 2; ++c)
        accL = __builtin_amdgcn_mfma_f32_16x16x32_bf16(onesf, pb[c], accL, 0, 0, 0);

      // O^T += V^T·P^T : av = single b128 (sigma-contiguous, XOR-swizzled)
#pragma unroll
      for (int c = 0; c < 2; ++c) {
#pragma unroll
        for (int dt = 0; dt < 4; ++dt) {
          const int idxv = ((4 * c + lhi) ^ (l7 ^ ((2 * dt + e2) & 7))) << 3;
          const bf16x8 av = *(const bf16x8*)&sVT[cur][dt * 16 + l15][idxv];
          accO[dt] = __builtin_amdgcn_mfma_f32_16x16x32_bf16(av, pb[c], accO[dt], 0, 0, 0);
        }
      }

      __syncthreads();   // the ONLY barrier per tile (drains DMA + orders bufs)
    }

    {
      const float inv  = 1.f / accL[0];
      const int   qrow = qwave + l15;
#pragma unroll
      for (int dt = 0; dt < 4; ++dt) {
        float4 o;
        o.x = accO[dt][0] * inv;
        o.y = accO[dt][1] * inv;
        o.z = accO[dt][2] * inv;
        o.w = accO[dt][3] * inv;
        *(float4*)&out[ob + (size_t)qrow * DM + h * HD + dt * 16 + lhi * 4] = o;
      }
    }
  }
}

extern "C" void kernel_launch(void* const* d_in, const int* in_sizes, int n_in,
                              void* d_out, int out_size, void* d_ws, size_t ws_size,
                              hipStream_t stream) {
  const float* x    = (const float*)d_in[0];
  const float* W    = (const float*)d_in[1];
  const float* bias = (const float*)d_in[2];
  float* out = (float*)d_out;

  // workspace: xb 16MB | Wb 6MB | Z2 32MB | VT 16MB  (= 70MB)
  bf16* xb = (bf16*)d_ws;
  bf16* Wb = xb + (size_t)NBAT * SEQ * DM;
  bf16* Z2 = Wb + (size_t)E3 * DM;
  bf16* VT = Z2 + (size_t)NBAT * SEQ * E2;

  cvt2_bf16_kernel<<<1536, 256, 0, stream>>>(x, xb, NBAT * SEQ * DM / 8,
                                             W, Wb, E3 * DM / 8);

  dim3 g1(NBAT * SEQ / BM, E3 / BN);
  qkv_gemm_kernel<<<g1, 256, 0, stream>>>(xb, Wb, bias, Z2, VT);

  attn_kernel<<<1024, 256, 0, stream>>>(Z2, VT, out);   // uniform, 4/CU
}